// Round 5
// baseline (1681.857 us; speedup 1.0000x reference)
//
#include <hip/hip_runtime.h>
#include <math.h>

// ---------------------------------------------------------------------------
// 2-layer GCN forward — ZERO global atomics.
// R12 = composition of the two MEASURED wins:
//  * R10: in-block CSR (sort edges to per-dst runs, one owner thread per dst,
//    register accumulation) removes per-feature LDS atomics (~3.2 cy each).
//  * R8: a 4MB gather table + nt edge stream + KERNEL-LAUNCH phase sync
//    => gathers are L2-hits (~free); FETCH == edge stream only.
// R10's src-windowing (inter-block lockstep) is REFUTED and removed.
// Pipeline:
//   k_count/colsum/scan/basefill/k_scatter : global dst-bucket counting sort
//        (SRCB=1, 4KB LDS) -> edge_g, kb[]
//   k_prep    : per-bucket degw -> dinv; xs0/1/2 = fp16x4(dinv*x) 8B-row
//               feature slices (4MB each)
//   k_csrsort : per-bucket P1 hist / P2 scan / P3 dst-sort -> edge2_g,
//               runstart[n] (2 LDS atomics/edge, the only ones left)
//   k_pass x3 : per-node register walk of edge2 (nt), gather xs_p (4MB,
//               L2-resident per launch), write agg_p[node] float4 (0 atomics)
//   k_mlp     : h2s = dinv*( relu(dinv*agg @ W1 + b1) @ W2 )
//   k_pull2_csr: per-node walk, h2s table 4MB L2-resident -> log_softmax
// Fallback: R1 atomic-scatter path if ws too small / n too large.
// ---------------------------------------------------------------------------

typedef unsigned long long u64;
typedef unsigned int u32;
typedef _Float16 f16;
typedef __attribute__((ext_vector_type(4))) _Float16 f16x4;

#define BKT    512        // nodes per dst bucket (collow = 9 bits)
#define NBMAX  1024       // max buckets (=> n <= 2^19, matches row:19 packing)
#define NBLK   256        // partition blocks for count/scatter

// ---------------- global dst-bucket counting sort ----------------

__global__ __launch_bounds__(256) void k_count(const int* __restrict__ col,
                                               u32* __restrict__ hist_g,
                                               int NB, int E, int CH) {
    __shared__ u32 cnt[NBMAX];
    for (int b = threadIdx.x; b < NB; b += 256) cnt[b] = 0;
    __syncthreads();
    int blk = blockIdx.x;
    int s = blk * CH, e = min(s + CH, E);
    for (int i = s + threadIdx.x; i < e; i += 256) {
        int c = __builtin_nontemporal_load(col + i);
        atomicAdd(&cnt[c >> 9], 1u);               // LDS atomic
    }
    __syncthreads();
    for (int b = threadIdx.x; b < NB; b += 256)
        hist_g[(size_t)blk * NB + b] = cnt[b];     // coalesced
}

// colsum[k] = sum_j hist[j][k]   (coalesced column reduction)
__global__ __launch_bounds__(256) void k_colsum(const u32* __restrict__ hist_g,
                                                u32* __restrict__ colsum, int NB) {
    int k = blockIdx.x * 256 + threadIdx.x;
    if (k >= NB) return;
    u32 s = 0;
    for (int j = 0; j < NBLK; j++) s += hist_g[(size_t)j * NB + k];
    colsum[k] = s;
}

// single-block chunked EXCLUSIVE scan in place
__global__ __launch_bounds__(256) void k_scan_sums32(u32* __restrict__ bsum, int nb) {
    __shared__ u32 s[256];
    __shared__ u32 carry;
    int t = threadIdx.x;
    if (t == 0) carry = 0;
    __syncthreads();
    int chunks = (nb + 255) / 256;
    for (int ch = 0; ch < chunks; ch++) {
        int i = ch * 256 + t;
        u32 v = (i < nb) ? bsum[i] : 0;
        s[t] = v;
        __syncthreads();
        for (int off = 1; off < 256; off <<= 1) {
            u32 u = (t >= off) ? s[t - off] : 0;
            __syncthreads();
            s[t] += u;
            __syncthreads();
        }
        u32 incl = s[t];
        u32 my_carry = carry;
        if (i < nb) bsum[i] = incl - v + my_carry;   // exclusive
        __syncthreads();
        if (t == 0) carry = my_carry + s[255];
        __syncthreads();
    }
}

// base[blk][k] = keybase[k] + prefix over blk of hist[.][k]  (coalesced)
__global__ __launch_bounds__(256) void k_basefill(const u32* __restrict__ hist_g,
                                                  const u32* __restrict__ keybase,
                                                  u32* __restrict__ base_g, int NB) {
    int k = blockIdx.x * 256 + threadIdx.x;
    if (k >= NB) return;
    u32 run = keybase[k];
    for (int j = 0; j < NBLK; j++) {
        base_g[(size_t)j * NB + k] = run;
        run += hist_g[(size_t)j * NB + k];
    }
}

__global__ __launch_bounds__(256) void k_scatter(const int* __restrict__ row,
                                                 const int* __restrict__ col,
                                                 const float* __restrict__ w,
                                                 const u32* __restrict__ base_g,
                                                 u64* __restrict__ edge_g,
                                                 int NB, int E, int CH) {
    __shared__ u32 cursor[NBMAX];
    int blk = blockIdx.x;
    for (int b = threadIdx.x; b < NB; b += 256)
        cursor[b] = base_g[(size_t)blk * NB + b];
    __syncthreads();
    int s = blk * CH, e = min(s + CH, E);
    for (int i = s + threadIdx.x; i < e; i += 256) {
        int c = __builtin_nontemporal_load(col + i);
        int r = __builtin_nontemporal_load(row + i);
        float wv = __builtin_nontemporal_load(w + i);
        int b = c >> 9;
        u32 pos = atomicAdd(&cursor[b], 1u);       // LDS atomic
        u64 rec = ((u64)__float_as_uint(wv) << 32)
                | ((u64)(u32)(c & 511) << 19) | (u64)(u32)r;
        edge_g[pos] = rec;
    }
}

// ---------------- prep: deg -> dinv, xs slices = fp16(dinv * x) ----------------

__global__ __launch_bounds__(256) void k_prep(const u64* __restrict__ edge_g,
                                              const u32* __restrict__ kb,
                                              const float* __restrict__ x,
                                              float* __restrict__ dinv_g,
                                              f16* __restrict__ xs0,
                                              f16* __restrict__ xs1,
                                              f16* __restrict__ xs2,
                                              int NB, int n, int E) {
    __shared__ float degw[BKT];
    int b = blockIdx.x;
    for (int j = threadIdx.x; j < BKT; j += 256) degw[j] = 1.0f;  // self-loop
    __syncthreads();
    int s = (int)kb[b];
    int e = (b + 1 < NB) ? (int)kb[b + 1] : E;
    for (int i = s + threadIdx.x; i < e; i += 256) {
        u64 rec = __builtin_nontemporal_load(edge_g + i);
        int cl = (int)(((u32)rec >> 19) & 511u);
        float wv = __uint_as_float((u32)(rec >> 32));
        atomicAdd(&degw[cl], wv);                  // LDS f32 atomic
    }
    __syncthreads();
    int node0 = b << 9;
    int nn = min(BKT, n - node0);
    for (int j = threadIdx.x; j < nn; j += 256) {
        int node = node0 + j;
        float dv = rsqrtf(degw[j]);
        dinv_g[node] = dv;
        const float* xp = x + (size_t)node * 11;
        f16x4 a, bq, c;
#pragma unroll
        for (int k = 0; k < 4; k++) a[k]  = (f16)(dv * xp[k]);
#pragma unroll
        for (int k = 0; k < 4; k++) bq[k] = (f16)(dv * xp[4 + k]);
        c[0] = (f16)(dv * xp[8]);
        c[1] = (f16)(dv * xp[9]);
        c[2] = (f16)(dv * xp[10]);
        c[3] = (f16)0.f;
        *(f16x4*)(xs0 + ((size_t)node << 2)) = a;
        *(f16x4*)(xs1 + ((size_t)node << 2)) = bq;
        *(f16x4*)(xs2 + ((size_t)node << 2)) = c;
    }
}

// ---------------- in-block CSR sort: edge_g (bucketed) -> edge2_g (dst-sorted) ----------------

__global__ __launch_bounds__(512) void k_csrsort(const u64* __restrict__ edge_g,
                                                 const u32* __restrict__ kb,
                                                 u64* __restrict__ edge2_g,
                                                 u32* __restrict__ runstart,
                                                 int NB, int n, int E) {
    __shared__ u32 cnt[BKT];
    __shared__ u32 off[BKT];
    __shared__ u32 cur[BKT];
    int t = threadIdx.x;
    int b = blockIdx.x;
    int node0 = b << 9;
    int s = (int)kb[b];
    int e = (b + 1 < NB) ? (int)kb[b + 1] : E;
    cnt[t] = 0;
    __syncthreads();
    // P1: per-dst histogram (1 LDS atomic / edge); plain load so the segment
    // stays L2-hot for P3's re-read
    for (int i = s + t; i < e; i += 512) {
        u32 lo = (u32)edge_g[i];
        atomicAdd(&cnt[(lo >> 19) & 511u], 1u);
    }
    __syncthreads();
    // P2: inclusive Hillis-Steele scan over 512
    off[t] = cnt[t];
    __syncthreads();
    for (int d = 1; d < 512; d <<= 1) {
        u32 v = (t >= d) ? off[t - d] : 0;
        __syncthreads();
        off[t] += v;
        __syncthreads();
    }
    u32 mystart = (u32)s + off[t] - cnt[t];     // exclusive start of run t
    cur[t] = mystart;
    runstart[node0 + t] = mystart;
    if (t == 511) runstart[node0 + 512] = (u32)e;   // boundary (next bucket dups)
    __syncthreads();
    // P3: scatter recs dst-sorted into edge2 (1 LDS atomic / edge)
    for (int i = s + t; i < e; i += 512) {
        u64 rec = edge_g[i];
        int cl = (int)(((u32)rec >> 19) & 511u);
        u32 pos = atomicAdd(&cur[cl], 1u);
        edge2_g[pos] = rec;
    }
}

// ---------------- slice pass: per-node register walk, 4MB table L2-resident ----------------

__global__ __launch_bounds__(256) void k_pass(const u64* __restrict__ edge2_g,
                                              const u32* __restrict__ runstart,
                                              const f16* __restrict__ xsp,
                                              float4* __restrict__ aggp, int n) {
    int node = blockIdx.x * 256 + threadIdx.x;
    if (node >= n) return;
    f16x4 selfv = *(const f16x4*)(xsp + ((size_t)node << 2));
    float a0 = (float)selfv[0], a1 = (float)selfv[1];
    float a2 = (float)selfv[2], a3 = (float)selfv[3];
    int p = (int)runstart[node], pe = (int)runstart[node + 1];
    for (; p + 3 < pe; p += 4) {
        u64 r0 = __builtin_nontemporal_load(edge2_g + p);
        u64 r1 = __builtin_nontemporal_load(edge2_g + p + 1);
        u64 r2 = __builtin_nontemporal_load(edge2_g + p + 2);
        u64 r3 = __builtin_nontemporal_load(edge2_g + p + 3);
        f16x4 g0 = *(const f16x4*)(xsp + ((size_t)((u32)r0 & 0x7FFFFu) << 2));
        f16x4 g1 = *(const f16x4*)(xsp + ((size_t)((u32)r1 & 0x7FFFFu) << 2));
        f16x4 g2 = *(const f16x4*)(xsp + ((size_t)((u32)r2 & 0x7FFFFu) << 2));
        f16x4 g3 = *(const f16x4*)(xsp + ((size_t)((u32)r3 & 0x7FFFFu) << 2));
        float w0 = __uint_as_float((u32)(r0 >> 32));
        float w1 = __uint_as_float((u32)(r1 >> 32));
        float w2 = __uint_as_float((u32)(r2 >> 32));
        float w3 = __uint_as_float((u32)(r3 >> 32));
        a0 += w0 * (float)g0[0] + w1 * (float)g1[0] + w2 * (float)g2[0] + w3 * (float)g3[0];
        a1 += w0 * (float)g0[1] + w1 * (float)g1[1] + w2 * (float)g2[1] + w3 * (float)g3[1];
        a2 += w0 * (float)g0[2] + w1 * (float)g1[2] + w2 * (float)g2[2] + w3 * (float)g3[2];
        a3 += w0 * (float)g0[3] + w1 * (float)g1[3] + w2 * (float)g2[3] + w3 * (float)g3[3];
    }
    for (; p < pe; p++) {
        u64 r0 = edge2_g[p];
        f16x4 g0 = *(const f16x4*)(xsp + ((size_t)((u32)r0 & 0x7FFFFu) << 2));
        float w0 = __uint_as_float((u32)(r0 >> 32));
        a0 += w0 * (float)g0[0];
        a1 += w0 * (float)g0[1];
        a2 += w0 * (float)g0[2];
        a3 += w0 * (float)g0[3];
    }
    float4 ov; ov.x = a0; ov.y = a1; ov.z = a2; ov.w = a3;
    aggp[node] = ov;
}

// ---------------- MLP epilogue: agg slices -> h2s ----------------

__global__ __launch_bounds__(256) void k_mlp(const float4* __restrict__ agg0,
                                             const float4* __restrict__ agg1,
                                             const float4* __restrict__ agg2,
                                             const float* __restrict__ dinv_g,
                                             const float* __restrict__ W1,
                                             const float* __restrict__ b1,
                                             const float* __restrict__ W2,
                                             float* __restrict__ h2s, int n) {
    __shared__ float sW1[176];
    __shared__ float sb1[16];
    __shared__ float sW2[32];
    for (int t = threadIdx.x; t < 176; t += 256) sW1[t] = W1[t];
    if (threadIdx.x < 16) sb1[threadIdx.x] = b1[threadIdx.x];
    if (threadIdx.x >= 64 && threadIdx.x < 96) sW2[threadIdx.x - 64] = W2[threadIdx.x - 64];
    __syncthreads();
    int node = blockIdx.x * 256 + threadIdx.x;
    if (node >= n) return;
    float dv = dinv_g[node];
    float4 v0 = agg0[node], v1 = agg1[node], v2 = agg2[node];
    float v[11];
    v[0] = dv * v0.x; v[1] = dv * v0.y; v[2]  = dv * v0.z; v[3] = dv * v0.w;
    v[4] = dv * v1.x; v[5] = dv * v1.y; v[6]  = dv * v1.z; v[7] = dv * v1.w;
    v[8] = dv * v2.x; v[9] = dv * v2.y; v[10] = dv * v2.z;
    float o0 = 0.f, o1 = 0.f;
#pragma unroll
    for (int f = 0; f < 16; f++) {
        float hh = sb1[f];
#pragma unroll
        for (int k = 0; k < 11; k++) hh += v[k] * sW1[k * 16 + f];
        hh = fmaxf(hh, 0.f);
        o0 += hh * sW2[f * 2 + 0];
        o1 += hh * sW2[f * 2 + 1];
    }
    float2 ov; ov.x = dv * o0; ov.y = dv * o1;   // h2s = dinv * h2
    *(float2*)(h2s + ((size_t)node << 1)) = ov;
}

// ---------------- CSR pull layer 2 (no LDS, no atomics) ----------------

__global__ __launch_bounds__(256) void k_pull2_csr(const u64* __restrict__ edge2_g,
                                                   const u32* __restrict__ runstart,
                                                   const float* __restrict__ h2s,
                                                   const float* __restrict__ dinv_g,
                                                   const float* __restrict__ b2,
                                                   float* __restrict__ out, int n) {
    int node = blockIdx.x * 256 + threadIdx.x;
    if (node >= n) return;
    float2 selfv = *(const float2*)(h2s + (size_t)node * 2);
    float a0 = selfv.x, a1 = selfv.y;
    int p = (int)runstart[node], pe = (int)runstart[node + 1];
    for (; p + 3 < pe; p += 4) {
        u64 r0 = __builtin_nontemporal_load(edge2_g + p);
        u64 r1 = __builtin_nontemporal_load(edge2_g + p + 1);
        u64 r2 = __builtin_nontemporal_load(edge2_g + p + 2);
        u64 r3 = __builtin_nontemporal_load(edge2_g + p + 3);
        float2 g0 = *(const float2*)(h2s + (size_t)((u32)r0 & 0x7FFFFu) * 2);
        float2 g1 = *(const float2*)(h2s + (size_t)((u32)r1 & 0x7FFFFu) * 2);
        float2 g2 = *(const float2*)(h2s + (size_t)((u32)r2 & 0x7FFFFu) * 2);
        float2 g3 = *(const float2*)(h2s + (size_t)((u32)r3 & 0x7FFFFu) * 2);
        float w0 = __uint_as_float((u32)(r0 >> 32));
        float w1 = __uint_as_float((u32)(r1 >> 32));
        float w2 = __uint_as_float((u32)(r2 >> 32));
        float w3 = __uint_as_float((u32)(r3 >> 32));
        a0 += w0 * g0.x + w1 * g1.x + w2 * g2.x + w3 * g3.x;
        a1 += w0 * g0.y + w1 * g1.y + w2 * g2.y + w3 * g3.y;
    }
    for (; p < pe; p++) {
        u64 r0 = edge2_g[p];
        float2 g0 = *(const float2*)(h2s + (size_t)((u32)r0 & 0x7FFFFu) * 2);
        float w0 = __uint_as_float((u32)(r0 >> 32));
        a0 += w0 * g0.x;
        a1 += w0 * g0.y;
    }
    float dv = dinv_g[node];
    float v0 = dv * a0 + b2[0];
    float v1 = dv * a1 + b2[1];
    float m = fmaxf(v0, v1);
    float lse = m + logf(expf(v0 - m) + expf(v1 - m));
    float2 ov; ov.x = v0 - lse; ov.y = v1 - lse;
    *(float2*)(out + (size_t)node * 2) = ov;
}

// ---------------- fallback atomic-scatter kernels (R1 proven path) ----------------

__global__ __launch_bounds__(256) void k_init_deg(float* deg, int n) {
    int i = blockIdx.x * blockDim.x + threadIdx.x;
    if (i < n) deg[i] = 1.0f;
}

__global__ __launch_bounds__(256) void k_deg_accum(const int* __restrict__ col,
                                                   const float* __restrict__ w,
                                                   float* __restrict__ deg, int E) {
    int i = blockIdx.x * blockDim.x + threadIdx.x;
    if (i < E) atomicAdd(&deg[col[i]], w[i]);
}

__global__ __launch_bounds__(256) void k_rsqrt(float* deg, int n) {
    int i = blockIdx.x * blockDim.x + threadIdx.x;
    if (i < n) {
        float d = deg[i];
        deg[i] = (d > 0.0f) ? rsqrtf(d) : 0.0f;
    }
}

__global__ __launch_bounds__(256) void k_gemm1_plain(const float* __restrict__ x,
                                                     const float* __restrict__ W1,
                                                     float* __restrict__ h1, int n) {
    __shared__ float sW[176];
    for (int t = threadIdx.x; t < 176; t += blockDim.x) sW[t] = W1[t];
    __syncthreads();
    int i = blockIdx.x * blockDim.x + threadIdx.x;
    if (i >= n) return;
    float xi[11];
#pragma unroll
    for (int k = 0; k < 11; k++) xi[k] = x[(size_t)i * 11 + k];
#pragma unroll
    for (int f = 0; f < 16; f++) {
        float acc = 0.0f;
#pragma unroll
        for (int k = 0; k < 11; k++) acc += xi[k] * sW[k * 16 + f];
        h1[(size_t)i * 16 + f] = acc;
    }
}

__global__ __launch_bounds__(256) void k_scatter16(const int* __restrict__ row,
                                                   const int* __restrict__ col,
                                                   const float* __restrict__ w,
                                                   const float* __restrict__ dinv,
                                                   const float* __restrict__ h1,
                                                   float* __restrict__ acc, int E) {
    int i = blockIdx.x * blockDim.x + threadIdx.x;
    if (i >= E) return;
    int r = row[i], c = col[i];
    float nw = dinv[r] * w[i] * dinv[c];
    const float4* hr = (const float4*)(h1 + (size_t)r * 16);
    float* o = acc + (size_t)c * 16;
#pragma unroll
    for (int q = 0; q < 4; q++) {
        float4 hv = hr[q];
        atomicAdd(o + q * 4 + 0, nw * hv.x);
        atomicAdd(o + q * 4 + 1, nw * hv.y);
        atomicAdd(o + q * 4 + 2, nw * hv.z);
        atomicAdd(o + q * 4 + 3, nw * hv.w);
    }
}

__global__ __launch_bounds__(256) void k_post1(const float* __restrict__ h1,
                                               const float* __restrict__ dinv,
                                               const float* __restrict__ b1,
                                               float* __restrict__ acc, int n) {
    int i = blockIdx.x * blockDim.x + threadIdx.x;
    if (i >= n) return;
    float dv = dinv[i];
    float cs = dv * dv;
#pragma unroll
    for (int f = 0; f < 16; f++) {
        float v = acc[(size_t)i * 16 + f] + cs * h1[(size_t)i * 16 + f] + b1[f];
        acc[(size_t)i * 16 + f] = v > 0.0f ? v : 0.0f;
    }
}

__global__ __launch_bounds__(256) void k_gemm2(const float* __restrict__ hrelu,
                                               const float* __restrict__ W2,
                                               float* __restrict__ h2, int n) {
    __shared__ float sW[32];
    for (int t = threadIdx.x; t < 32; t += blockDim.x) sW[t] = W2[t];
    __syncthreads();
    int i = blockIdx.x * blockDim.x + threadIdx.x;
    if (i >= n) return;
    float a0 = 0.0f, a1 = 0.0f;
#pragma unroll
    for (int f = 0; f < 16; f++) {
        float h = hrelu[(size_t)i * 16 + f];
        a0 += h * sW[f * 2 + 0];
        a1 += h * sW[f * 2 + 1];
    }
    h2[(size_t)i * 2 + 0] = a0;
    h2[(size_t)i * 2 + 1] = a1;
}

__global__ __launch_bounds__(256) void k_scatter2(const int* __restrict__ row,
                                                  const int* __restrict__ col,
                                                  const float* __restrict__ w,
                                                  const float* __restrict__ dinv,
                                                  const float* __restrict__ h2,
                                                  float* __restrict__ out, int E) {
    int i = blockIdx.x * blockDim.x + threadIdx.x;
    if (i >= E) return;
    int r = row[i], c = col[i];
    float nw = dinv[r] * w[i] * dinv[c];
    atomicAdd(&out[(size_t)c * 2 + 0], nw * h2[(size_t)r * 2 + 0]);
    atomicAdd(&out[(size_t)c * 2 + 1], nw * h2[(size_t)r * 2 + 1]);
}

__global__ __launch_bounds__(256) void k_final(const float* __restrict__ h2,
                                               const float* __restrict__ dinv,
                                               const float* __restrict__ b2,
                                               float* __restrict__ out, int n) {
    int i = blockIdx.x * blockDim.x + threadIdx.x;
    if (i >= n) return;
    float dv = dinv[i];
    float cs = dv * dv;
    float v0 = out[(size_t)i * 2 + 0] + cs * h2[(size_t)i * 2 + 0] + b2[0];
    float v1 = out[(size_t)i * 2 + 1] + cs * h2[(size_t)i * 2 + 1] + b2[1];
    float m = fmaxf(v0, v1);
    float lse = m + logf(expf(v0 - m) + expf(v1 - m));
    out[(size_t)i * 2 + 0] = v0 - lse;
    out[(size_t)i * 2 + 1] = v1 - lse;
}

// ---------------- launch ----------------

static inline size_t align64(size_t x) { return (x + 63) & ~(size_t)63; }

extern "C" void kernel_launch(void* const* d_in, const int* in_sizes, int n_in,
                              void* d_out, int out_size, void* d_ws, size_t ws_size,
                              hipStream_t stream) {
    const float* x  = (const float*)d_in[0];
    const int*   ei = (const int*)d_in[1];
    const float* ew = (const float*)d_in[2];
    const float* W1 = (const float*)d_in[3];
    const float* b1 = (const float*)d_in[4];
    const float* W2 = (const float*)d_in[5];
    const float* b2 = (const float*)d_in[6];

    const int n = in_sizes[0] / 11;
    const int E = in_sizes[2];
    const int* rowp = ei;       // sources
    const int* colp = ei + E;   // targets

    const int TB = 256;
    const int gN = (n + TB - 1) / TB;
    const int gE = (E + TB - 1) / TB;

    const int NB = (n + BKT - 1) / BKT;            // dst buckets
    const int CH = (E + NBLK - 1) / NBLK;          // edges per partition block

    float* outf = (float*)d_out;

    // --- workspace layout ---
    char* base = (char*)d_ws;
    size_t M = (size_t)NBLK * NB;
    size_t o_hist = 0;                                        // u32 M
    size_t o_base = align64(o_hist + M * 4);                  // u32 M
    size_t o_kb   = align64(o_base + M * 4);                  // u32 NB+2
    size_t o_dinv = align64(o_kb + (size_t)(NB + 2) * 4);     // f32 n
    size_t o_xs0  = align64(o_dinv + (size_t)n * 4);          // f16 4n (8B rows)
    size_t o_xs1  = align64(o_xs0 + (size_t)n * 8);
    size_t o_xs2  = align64(o_xs1 + (size_t)n * 8);
    size_t o_ag0  = align64(o_xs2 + (size_t)n * 8);           // f32x4 n
    size_t o_ag1  = align64(o_ag0 + (size_t)n * 16);
    size_t o_ag2  = align64(o_ag1 + (size_t)n * 16);
    size_t o_h2   = align64(o_ag2 + (size_t)n * 16);          // f32 2n
    size_t o_run  = align64(o_h2 + (size_t)n * 2 * 4);        // u32 n+BKT+2
    size_t o_edge = align64(o_run + (size_t)(n + BKT + 2) * 4); // u64 E
    size_t o_edge2 = align64(o_edge + (size_t)E * 8);         // u64 E
    size_t needed = align64(o_edge2 + (size_t)E * 8);

    if (ws_size >= needed && n <= (1 << 19) && NB <= NBMAX) {
        u32*    hist_g = (u32*)(base + o_hist);
        u32*    base_g = (u32*)(base + o_base);
        u32*    kb     = (u32*)(base + o_kb);
        float*  dinv_g = (float*)(base + o_dinv);
        f16*    xs0    = (f16*)(base + o_xs0);
        f16*    xs1    = (f16*)(base + o_xs1);
        f16*    xs2    = (f16*)(base + o_xs2);
        float4* agg0   = (float4*)(base + o_ag0);
        float4* agg1   = (float4*)(base + o_ag1);
        float4* agg2   = (float4*)(base + o_ag2);
        float*  h2s    = (float*)(base + o_h2);
        u32*    runst  = (u32*)(base + o_run);
        u64*    edge_g = (u64*)(base + o_edge);
        u64*    edge2_g = (u64*)(base + o_edge2);

        const int KBg = (NB + 255) / 256;

        k_count<<<NBLK, TB, 0, stream>>>(colp, hist_g, NB, E, CH);
        k_colsum<<<KBg, TB, 0, stream>>>(hist_g, kb, NB);
        k_scan_sums32<<<1, TB, 0, stream>>>(kb, NB);           // kb -> exclusive bases
        k_basefill<<<KBg, TB, 0, stream>>>(hist_g, kb, base_g, NB);
        k_scatter<<<NBLK, TB, 0, stream>>>(rowp, colp, ew, base_g, edge_g, NB, E, CH);
        k_prep<<<NB, TB, 0, stream>>>(edge_g, kb, x, dinv_g, xs0, xs1, xs2, NB, n, E);
        k_csrsort<<<NB, 512, 0, stream>>>(edge_g, kb, edge2_g, runst, NB, n, E);
        k_pass<<<gN, TB, 0, stream>>>(edge2_g, runst, xs0, agg0, n);
        k_pass<<<gN, TB, 0, stream>>>(edge2_g, runst, xs1, agg1, n);
        k_pass<<<gN, TB, 0, stream>>>(edge2_g, runst, xs2, agg2, n);
        k_mlp<<<gN, TB, 0, stream>>>(agg0, agg1, agg2, dinv_g, W1, b1, W2, h2s, n);
        k_pull2_csr<<<gN, TB, 0, stream>>>(edge2_g, runst, h2s, dinv_g, b2, outf, n);
    } else {
        // fallback: atomic-scatter path (R1)
        float* ws   = (float*)d_ws;
        float* dinv = ws;
        float* h1   = ws + (size_t)n;
        float* acc1 = ws + (size_t)n * 17;

        k_init_deg<<<gN, TB, 0, stream>>>(dinv, n);
        k_deg_accum<<<gE, TB, 0, stream>>>(colp, ew, dinv, E);
        k_rsqrt<<<gN, TB, 0, stream>>>(dinv, n);

        k_gemm1_plain<<<gN, TB, 0, stream>>>(x, W1, h1, n);
        hipMemsetAsync(acc1, 0, (size_t)n * 16 * sizeof(float), stream);
        k_scatter16<<<gE, TB, 0, stream>>>(rowp, colp, ew, dinv, h1, acc1, E);
        k_post1<<<gN, TB, 0, stream>>>(h1, dinv, b1, acc1, n);

        float* h2 = h1;
        k_gemm2<<<gN, TB, 0, stream>>>(acc1, W2, h2, n);
        hipMemsetAsync(outf, 0, (size_t)n * 2 * sizeof(float), stream);
        k_scatter2<<<gE, TB, 0, stream>>>(rowp, colp, ew, dinv, h2, outf, E);
        k_final<<<gN, TB, 0, stream>>>(h2, dinv, b2, outf, n);
    }
}

// Round 6
// 1432.464 us; speedup vs baseline: 1.1741x; 1.1741x over previous
//
#include <hip/hip_runtime.h>
#include <math.h>

// ---------------------------------------------------------------------------
// 2-layer GCN forward — ZERO global atomics.
// R13 (on R12's measured skeleton):
//  * k_scatter was 306us with 485MB WRITE for 128MB payload (partial-line
//    thrash). Fix: chunked local-sort staging — per 4096-edge chunk,
//    LDS hist+scan+stage in bucket-sorted order, flush with consecutive
//    lanes -> consecutive addresses. NBLK 256->512.
//  * k_csrsort P3 gets the same staged flush (runs of ~8 over 512 dsts).
//  * k_csrsort P1 also accumulates degw (1 extra LDS f32 atomic/edge) and
//    writes dinv_g -> k_prep no longer reads the 128MB edge array.
// Pipeline:
//   k_count/colsum/scan/basefill : dst-bucket bases (512 partitions)
//   k_scatter : staged counting-sort scatter -> edge_g (bucketed)
//   k_csrsort : per-bucket hist/scan -> runstart, dinv; staged dst-sort
//               -> edge2_g
//   k_prep    : node-parallel: xs0/1/2 = fp16x4(dinv*x) slices (4MB each)
//   k_pass x3 : per-node register walk of edge2 (nt), gather 4MB slice
//               (L2-resident per launch), write agg float4 (0 atomics)
//   k_mlp     : h2s = dinv*( relu(dinv*agg @ W1 + b1) @ W2 )
//   k_pull2_csr: per-node walk, h2s 4MB L2-resident -> log_softmax
// Fallback: R1 atomic-scatter path if ws too small / n too large.
// ---------------------------------------------------------------------------

typedef unsigned long long u64;
typedef unsigned int u32;
typedef unsigned short u16;
typedef _Float16 f16;
typedef __attribute__((ext_vector_type(4))) _Float16 f16x4;

#define BKT    512        // nodes per dst bucket (collow = 9 bits)
#define NBMAX  1024       // max buckets (=> n <= 2^19, matches row:19 packing)
#define NBLK   512        // partition blocks for count/scatter
#define CHUNK  4096       // staged chunk (8 edges x 512 threads)

// ---------------- count / scan / basefill ----------------

__global__ __launch_bounds__(256) void k_count(const int* __restrict__ col,
                                               u32* __restrict__ hist_g,
                                               int NB, int E, int CH) {
    __shared__ u32 cnt[NBMAX];
    for (int b = threadIdx.x; b < NB; b += 256) cnt[b] = 0;
    __syncthreads();
    int blk = blockIdx.x;
    int s = blk * CH, e = min(s + CH, E);
    for (int i = s + threadIdx.x; i < e; i += 256) {
        int c = __builtin_nontemporal_load(col + i);
        atomicAdd(&cnt[c >> 9], 1u);               // LDS atomic
    }
    __syncthreads();
    for (int b = threadIdx.x; b < NB; b += 256)
        hist_g[(size_t)blk * NB + b] = cnt[b];     // coalesced
}

__global__ __launch_bounds__(256) void k_colsum(const u32* __restrict__ hist_g,
                                                u32* __restrict__ colsum, int NB) {
    int k = blockIdx.x * 256 + threadIdx.x;
    if (k >= NB) return;
    u32 s = 0;
    for (int j = 0; j < NBLK; j++) s += hist_g[(size_t)j * NB + k];
    colsum[k] = s;
}

__global__ __launch_bounds__(256) void k_scan_sums32(u32* __restrict__ bsum, int nb) {
    __shared__ u32 s[256];
    __shared__ u32 carry;
    int t = threadIdx.x;
    if (t == 0) carry = 0;
    __syncthreads();
    int chunks = (nb + 255) / 256;
    for (int ch = 0; ch < chunks; ch++) {
        int i = ch * 256 + t;
        u32 v = (i < nb) ? bsum[i] : 0;
        s[t] = v;
        __syncthreads();
        for (int off = 1; off < 256; off <<= 1) {
            u32 u = (t >= off) ? s[t - off] : 0;
            __syncthreads();
            s[t] += u;
            __syncthreads();
        }
        u32 incl = s[t];
        u32 my_carry = carry;
        if (i < nb) bsum[i] = incl - v + my_carry;   // exclusive
        __syncthreads();
        if (t == 0) carry = my_carry + s[255];
        __syncthreads();
    }
}

__global__ __launch_bounds__(256) void k_basefill(const u32* __restrict__ hist_g,
                                                  const u32* __restrict__ keybase,
                                                  u32* __restrict__ base_g, int NB) {
    int k = blockIdx.x * 256 + threadIdx.x;
    if (k >= NB) return;
    u32 run = keybase[k];
    for (int j = 0; j < NBLK; j++) {
        base_g[(size_t)j * NB + k] = run;
        run += hist_g[(size_t)j * NB + k];
    }
}

// ---------------- staged counting-sort scatter ----------------
// Per chunk: LDS hist (rank via atomic return), block scan, stage records in
// bucket-sorted order, flush linearly (consecutive lanes -> consecutive
// addresses within each bucket run), advance cursors. ~54KB LDS.

__global__ __launch_bounds__(512) void k_scatter(const int* __restrict__ row,
                                                 const int* __restrict__ col,
                                                 const float* __restrict__ w,
                                                 const u32* __restrict__ base_g,
                                                 u64* __restrict__ edge_g,
                                                 int NB, int E, int CH) {
    __shared__ u64 stage[CHUNK];      // 32KB
    __shared__ u16 skey[CHUNK];       // 8KB
    __shared__ u32 cursor[NBMAX];     // 4KB
    __shared__ u32 ccnt[NBMAX];       // 4KB
    __shared__ u32 cbase[NBMAX];      // 4KB
    __shared__ u32 sscan[512];        // 2KB
    int t = threadIdx.x;
    int blk = blockIdx.x;
    for (int b = t; b < NB; b += 512) cursor[b] = base_g[(size_t)blk * NB + b];
    int s = blk * CH, e = min(s + CH, E);
    for (int c0 = s; c0 < e; c0 += CHUNK) {
        int cend = min(c0 + CHUNK, e);
        for (int b = t; b < NB; b += 512) ccnt[b] = 0;
        __syncthreads();
        u64 rec[8]; u32 rnk[8]; int key[8];
#pragma unroll
        for (int q = 0; q < 8; q++) {
            int i = c0 + q * 512 + t;
            if (i < cend) {
                int c  = __builtin_nontemporal_load(col + i);
                int r  = __builtin_nontemporal_load(row + i);
                float wv = __builtin_nontemporal_load(w + i);
                int k = c >> 9;
                rec[q] = ((u64)__float_as_uint(wv) << 32)
                       | ((u64)(u32)(c & 511) << 19) | (u64)(u32)r;
                key[q] = k;
                rnk[q] = atomicAdd(&ccnt[k], 1u);
            } else key[q] = -1;
        }
        __syncthreads();
        // exclusive scan of ccnt[0..NB) -> cbase ; 512 threads x 2 keys
        u32 a0 = (2 * t     < NB) ? ccnt[2 * t]     : 0;
        u32 a1 = (2 * t + 1 < NB) ? ccnt[2 * t + 1] : 0;
        sscan[t] = a0 + a1;
        __syncthreads();
        for (int d = 1; d < 512; d <<= 1) {
            u32 v = (t >= d) ? sscan[t - d] : 0;
            __syncthreads();
            sscan[t] += v;
            __syncthreads();
        }
        u32 bse = (t > 0) ? sscan[t - 1] : 0;
        if (2 * t     < NB) cbase[2 * t]     = bse;
        if (2 * t + 1 < NB) cbase[2 * t + 1] = bse + a0;
        __syncthreads();
        // stage in bucket-sorted order
#pragma unroll
        for (int q = 0; q < 8; q++) {
            if (key[q] >= 0) {
                u32 slot = cbase[key[q]] + rnk[q];
                stage[slot] = rec[q];
                skey[slot] = (u16)key[q];
            }
        }
        __syncthreads();
        // coalesced flush
        int tot = cend - c0;
        for (int j = t; j < tot; j += 512) {
            int k = skey[j];
            edge_g[cursor[k] + (u32)j - cbase[k]] = stage[j];
        }
        __syncthreads();
        for (int b = t; b < NB; b += 512) cursor[b] += ccnt[b];
        __syncthreads();
    }
}

// ---------------- csrsort: hist+degw -> runstart,dinv ; staged dst-sort ----------------

__global__ __launch_bounds__(512) void k_csrsort(const u64* __restrict__ edge_g,
                                                 const u32* __restrict__ kb,
                                                 u64* __restrict__ edge2_g,
                                                 u32* __restrict__ runstart,
                                                 float* __restrict__ dinv_g,
                                                 int NB, int n, int E) {
    __shared__ u64 stage[CHUNK];      // 32KB
    __shared__ u16 skey[CHUNK];       // 8KB
    __shared__ u32 cnt[BKT];          // 2KB
    __shared__ float sdeg[BKT];       // 2KB
    __shared__ u32 cur[BKT];          // 2KB
    __shared__ u32 ccnt[BKT];         // 2KB
    __shared__ u32 cbase[BKT];        // 2KB
    int t = threadIdx.x;              // 512 threads; t owns dst t
    int b = blockIdx.x;
    int node0 = b << 9;
    int s = (int)kb[b];
    int e = (b + 1 < NB) ? (int)kb[b + 1] : E;
    cnt[t] = 0;
    sdeg[t] = 1.0f;                   // self-loop weight
    __syncthreads();
    // P1: per-dst histogram + weighted degree (2 LDS atomics/edge; nt stream)
    for (int i = s + t; i < e; i += 512) {
        u64 rec = __builtin_nontemporal_load(edge_g + i);
        int cl = (int)(((u32)rec >> 19) & 511u);
        atomicAdd(&cnt[cl], 1u);
        atomicAdd(&sdeg[cl], __uint_as_float((u32)(rec >> 32)));
    }
    __syncthreads();
    // P2: inclusive scan of cnt (via ccnt as temp) -> run starts
    ccnt[t] = cnt[t];
    __syncthreads();
    for (int d = 1; d < 512; d <<= 1) {
        u32 v = (t >= d) ? ccnt[t - d] : 0;
        __syncthreads();
        ccnt[t] += v;
        __syncthreads();
    }
    u32 mystart = (u32)s + ccnt[t] - cnt[t];
    cur[t] = mystart;
    runstart[node0 + t] = mystart;
    if (t == 511) runstart[node0 + 512] = (u32)e;
    if (node0 + t < n) dinv_g[node0 + t] = rsqrtf(sdeg[t]);
    __syncthreads();
    // P3: chunked staged dst-sort (1 LDS atomic/edge + coalesced flush)
    for (int c0 = s; c0 < e; c0 += CHUNK) {
        int cend = min(c0 + CHUNK, e);
        ccnt[t] = 0;
        __syncthreads();
        u64 rec[8]; u32 rnk[8]; int key[8];
#pragma unroll
        for (int q = 0; q < 8; q++) {
            int i = c0 + q * 512 + t;
            if (i < cend) {
                u64 r = __builtin_nontemporal_load(edge_g + i);
                int cl = (int)(((u32)r >> 19) & 511u);
                rec[q] = r;
                key[q] = cl;
                rnk[q] = atomicAdd(&ccnt[cl], 1u);
            } else key[q] = -1;
        }
        __syncthreads();
        // exclusive scan ccnt -> cbase (in place trick)
        cbase[t] = ccnt[t];
        __syncthreads();
        for (int d = 1; d < 512; d <<= 1) {
            u32 v = (t >= d) ? cbase[t - d] : 0;
            __syncthreads();
            cbase[t] += v;
            __syncthreads();
        }
        u32 myexc = cbase[t] - ccnt[t];
        __syncthreads();
        cbase[t] = myexc;
        __syncthreads();
#pragma unroll
        for (int q = 0; q < 8; q++) {
            if (key[q] >= 0) {
                u32 slot = cbase[key[q]] + rnk[q];
                stage[slot] = rec[q];
                skey[slot] = (u16)key[q];
            }
        }
        __syncthreads();
        int tot = cend - c0;
        for (int j = t; j < tot; j += 512) {
            int k = skey[j];
            edge2_g[cur[k] + (u32)j - cbase[k]] = stage[j];
        }
        __syncthreads();
        cur[t] += ccnt[t];
        __syncthreads();
    }
}

// ---------------- prep (node-parallel): xs slices = fp16(dinv * x) ----------------

__global__ __launch_bounds__(256) void k_prep(const float* __restrict__ x,
                                              const float* __restrict__ dinv_g,
                                              f16* __restrict__ xs0,
                                              f16* __restrict__ xs1,
                                              f16* __restrict__ xs2, int n) {
    int node = blockIdx.x * 256 + threadIdx.x;
    if (node >= n) return;
    float dv = dinv_g[node];
    const float* xp = x + (size_t)node * 11;
    f16x4 a, bq, c;
#pragma unroll
    for (int k = 0; k < 4; k++) a[k]  = (f16)(dv * xp[k]);
#pragma unroll
    for (int k = 0; k < 4; k++) bq[k] = (f16)(dv * xp[4 + k]);
    c[0] = (f16)(dv * xp[8]);
    c[1] = (f16)(dv * xp[9]);
    c[2] = (f16)(dv * xp[10]);
    c[3] = (f16)0.f;
    *(f16x4*)(xs0 + ((size_t)node << 2)) = a;
    *(f16x4*)(xs1 + ((size_t)node << 2)) = bq;
    *(f16x4*)(xs2 + ((size_t)node << 2)) = c;
}

// ---------------- slice pass: per-node register walk, 4MB table L2-resident ----------------

__global__ __launch_bounds__(256) void k_pass(const u64* __restrict__ edge2_g,
                                              const u32* __restrict__ runstart,
                                              const f16* __restrict__ xsp,
                                              float4* __restrict__ aggp, int n) {
    int node = blockIdx.x * 256 + threadIdx.x;
    if (node >= n) return;
    f16x4 selfv = *(const f16x4*)(xsp + ((size_t)node << 2));
    float a0 = (float)selfv[0], a1 = (float)selfv[1];
    float a2 = (float)selfv[2], a3 = (float)selfv[3];
    int p = (int)runstart[node], pe = (int)runstart[node + 1];
    for (; p + 3 < pe; p += 4) {
        u64 r0 = __builtin_nontemporal_load(edge2_g + p);
        u64 r1 = __builtin_nontemporal_load(edge2_g + p + 1);
        u64 r2 = __builtin_nontemporal_load(edge2_g + p + 2);
        u64 r3 = __builtin_nontemporal_load(edge2_g + p + 3);
        f16x4 g0 = *(const f16x4*)(xsp + ((size_t)((u32)r0 & 0x7FFFFu) << 2));
        f16x4 g1 = *(const f16x4*)(xsp + ((size_t)((u32)r1 & 0x7FFFFu) << 2));
        f16x4 g2 = *(const f16x4*)(xsp + ((size_t)((u32)r2 & 0x7FFFFu) << 2));
        f16x4 g3 = *(const f16x4*)(xsp + ((size_t)((u32)r3 & 0x7FFFFu) << 2));
        float w0 = __uint_as_float((u32)(r0 >> 32));
        float w1 = __uint_as_float((u32)(r1 >> 32));
        float w2 = __uint_as_float((u32)(r2 >> 32));
        float w3 = __uint_as_float((u32)(r3 >> 32));
        a0 += w0 * (float)g0[0] + w1 * (float)g1[0] + w2 * (float)g2[0] + w3 * (float)g3[0];
        a1 += w0 * (float)g0[1] + w1 * (float)g1[1] + w2 * (float)g2[1] + w3 * (float)g3[1];
        a2 += w0 * (float)g0[2] + w1 * (float)g1[2] + w2 * (float)g2[2] + w3 * (float)g3[2];
        a3 += w0 * (float)g0[3] + w1 * (float)g1[3] + w2 * (float)g2[3] + w3 * (float)g3[3];
    }
    for (; p < pe; p++) {
        u64 r0 = edge2_g[p];
        f16x4 g0 = *(const f16x4*)(xsp + ((size_t)((u32)r0 & 0x7FFFFu) << 2));
        float w0 = __uint_as_float((u32)(r0 >> 32));
        a0 += w0 * (float)g0[0];
        a1 += w0 * (float)g0[1];
        a2 += w0 * (float)g0[2];
        a3 += w0 * (float)g0[3];
    }
    float4 ov; ov.x = a0; ov.y = a1; ov.z = a2; ov.w = a3;
    aggp[node] = ov;
}

// ---------------- MLP epilogue: agg slices -> h2s ----------------

__global__ __launch_bounds__(256) void k_mlp(const float4* __restrict__ agg0,
                                             const float4* __restrict__ agg1,
                                             const float4* __restrict__ agg2,
                                             const float* __restrict__ dinv_g,
                                             const float* __restrict__ W1,
                                             const float* __restrict__ b1,
                                             const float* __restrict__ W2,
                                             float* __restrict__ h2s, int n) {
    __shared__ float sW1[176];
    __shared__ float sb1[16];
    __shared__ float sW2[32];
    for (int t = threadIdx.x; t < 176; t += 256) sW1[t] = W1[t];
    if (threadIdx.x < 16) sb1[threadIdx.x] = b1[threadIdx.x];
    if (threadIdx.x >= 64 && threadIdx.x < 96) sW2[threadIdx.x - 64] = W2[threadIdx.x - 64];
    __syncthreads();
    int node = blockIdx.x * 256 + threadIdx.x;
    if (node >= n) return;
    float dv = dinv_g[node];
    float4 v0 = agg0[node], v1 = agg1[node], v2 = agg2[node];
    float v[11];
    v[0] = dv * v0.x; v[1] = dv * v0.y; v[2]  = dv * v0.z; v[3] = dv * v0.w;
    v[4] = dv * v1.x; v[5] = dv * v1.y; v[6]  = dv * v1.z; v[7] = dv * v1.w;
    v[8] = dv * v2.x; v[9] = dv * v2.y; v[10] = dv * v2.z;
    float o0 = 0.f, o1 = 0.f;
#pragma unroll
    for (int f = 0; f < 16; f++) {
        float hh = sb1[f];
#pragma unroll
        for (int k = 0; k < 11; k++) hh += v[k] * sW1[k * 16 + f];
        hh = fmaxf(hh, 0.f);
        o0 += hh * sW2[f * 2 + 0];
        o1 += hh * sW2[f * 2 + 1];
    }
    float2 ov; ov.x = dv * o0; ov.y = dv * o1;   // h2s = dinv * h2
    *(float2*)(h2s + ((size_t)node << 1)) = ov;
}

// ---------------- CSR pull layer 2 (no LDS, no atomics) ----------------

__global__ __launch_bounds__(256) void k_pull2_csr(const u64* __restrict__ edge2_g,
                                                   const u32* __restrict__ runstart,
                                                   const float* __restrict__ h2s,
                                                   const float* __restrict__ dinv_g,
                                                   const float* __restrict__ b2,
                                                   float* __restrict__ out, int n) {
    int node = blockIdx.x * 256 + threadIdx.x;
    if (node >= n) return;
    float2 selfv = *(const float2*)(h2s + (size_t)node * 2);
    float a0 = selfv.x, a1 = selfv.y;
    int p = (int)runstart[node], pe = (int)runstart[node + 1];
    for (; p + 3 < pe; p += 4) {
        u64 r0 = __builtin_nontemporal_load(edge2_g + p);
        u64 r1 = __builtin_nontemporal_load(edge2_g + p + 1);
        u64 r2 = __builtin_nontemporal_load(edge2_g + p + 2);
        u64 r3 = __builtin_nontemporal_load(edge2_g + p + 3);
        float2 g0 = *(const float2*)(h2s + (size_t)((u32)r0 & 0x7FFFFu) * 2);
        float2 g1 = *(const float2*)(h2s + (size_t)((u32)r1 & 0x7FFFFu) * 2);
        float2 g2 = *(const float2*)(h2s + (size_t)((u32)r2 & 0x7FFFFu) * 2);
        float2 g3 = *(const float2*)(h2s + (size_t)((u32)r3 & 0x7FFFFu) * 2);
        float w0 = __uint_as_float((u32)(r0 >> 32));
        float w1 = __uint_as_float((u32)(r1 >> 32));
        float w2 = __uint_as_float((u32)(r2 >> 32));
        float w3 = __uint_as_float((u32)(r3 >> 32));
        a0 += w0 * g0.x + w1 * g1.x + w2 * g2.x + w3 * g3.x;
        a1 += w0 * g0.y + w1 * g1.y + w2 * g2.y + w3 * g3.y;
    }
    for (; p < pe; p++) {
        u64 r0 = edge2_g[p];
        float2 g0 = *(const float2*)(h2s + (size_t)((u32)r0 & 0x7FFFFu) * 2);
        float w0 = __uint_as_float((u32)(r0 >> 32));
        a0 += w0 * g0.x;
        a1 += w0 * g0.y;
    }
    float dv = dinv_g[node];
    float v0 = dv * a0 + b2[0];
    float v1 = dv * a1 + b2[1];
    float m = fmaxf(v0, v1);
    float lse = m + logf(expf(v0 - m) + expf(v1 - m));
    float2 ov; ov.x = v0 - lse; ov.y = v1 - lse;
    *(float2*)(out + (size_t)node * 2) = ov;
}

// ---------------- fallback atomic-scatter kernels (R1 proven path) ----------------

__global__ __launch_bounds__(256) void k_init_deg(float* deg, int n) {
    int i = blockIdx.x * blockDim.x + threadIdx.x;
    if (i < n) deg[i] = 1.0f;
}

__global__ __launch_bounds__(256) void k_deg_accum(const int* __restrict__ col,
                                                   const float* __restrict__ w,
                                                   float* __restrict__ deg, int E) {
    int i = blockIdx.x * blockDim.x + threadIdx.x;
    if (i < E) atomicAdd(&deg[col[i]], w[i]);
}

__global__ __launch_bounds__(256) void k_rsqrt(float* deg, int n) {
    int i = blockIdx.x * blockDim.x + threadIdx.x;
    if (i < n) {
        float d = deg[i];
        deg[i] = (d > 0.0f) ? rsqrtf(d) : 0.0f;
    }
}

__global__ __launch_bounds__(256) void k_gemm1_plain(const float* __restrict__ x,
                                                     const float* __restrict__ W1,
                                                     float* __restrict__ h1, int n) {
    __shared__ float sW[176];
    for (int t = threadIdx.x; t < 176; t += blockDim.x) sW[t] = W1[t];
    __syncthreads();
    int i = blockIdx.x * blockDim.x + threadIdx.x;
    if (i >= n) return;
    float xi[11];
#pragma unroll
    for (int k = 0; k < 11; k++) xi[k] = x[(size_t)i * 11 + k];
#pragma unroll
    for (int f = 0; f < 16; f++) {
        float acc = 0.0f;
#pragma unroll
        for (int k = 0; k < 11; k++) acc += xi[k] * sW[k * 16 + f];
        h1[(size_t)i * 16 + f] = acc;
    }
}

__global__ __launch_bounds__(256) void k_scatter16(const int* __restrict__ row,
                                                   const int* __restrict__ col,
                                                   const float* __restrict__ w,
                                                   const float* __restrict__ dinv,
                                                   const float* __restrict__ h1,
                                                   float* __restrict__ acc, int E) {
    int i = blockIdx.x * blockDim.x + threadIdx.x;
    if (i >= E) return;
    int r = row[i], c = col[i];
    float nw = dinv[r] * w[i] * dinv[c];
    const float4* hr = (const float4*)(h1 + (size_t)r * 16);
    float* o = acc + (size_t)c * 16;
#pragma unroll
    for (int q = 0; q < 4; q++) {
        float4 hv = hr[q];
        atomicAdd(o + q * 4 + 0, nw * hv.x);
        atomicAdd(o + q * 4 + 1, nw * hv.y);
        atomicAdd(o + q * 4 + 2, nw * hv.z);
        atomicAdd(o + q * 4 + 3, nw * hv.w);
    }
}

__global__ __launch_bounds__(256) void k_post1(const float* __restrict__ h1,
                                               const float* __restrict__ dinv,
                                               const float* __restrict__ b1,
                                               float* __restrict__ acc, int n) {
    int i = blockIdx.x * blockDim.x + threadIdx.x;
    if (i >= n) return;
    float dv = dinv[i];
    float cs = dv * dv;
#pragma unroll
    for (int f = 0; f < 16; f++) {
        float v = acc[(size_t)i * 16 + f] + cs * h1[(size_t)i * 16 + f] + b1[f];
        acc[(size_t)i * 16 + f] = v > 0.0f ? v : 0.0f;
    }
}

__global__ __launch_bounds__(256) void k_gemm2(const float* __restrict__ hrelu,
                                               const float* __restrict__ W2,
                                               float* __restrict__ h2, int n) {
    __shared__ float sW[32];
    for (int t = threadIdx.x; t < 32; t += blockDim.x) sW[t] = W2[t];
    __syncthreads();
    int i = blockIdx.x * blockDim.x + threadIdx.x;
    if (i >= n) return;
    float a0 = 0.0f, a1 = 0.0f;
#pragma unroll
    for (int f = 0; f < 16; f++) {
        float h = hrelu[(size_t)i * 16 + f];
        a0 += h * sW[f * 2 + 0];
        a1 += h * sW[f * 2 + 1];
    }
    h2[(size_t)i * 2 + 0] = a0;
    h2[(size_t)i * 2 + 1] = a1;
}

__global__ __launch_bounds__(256) void k_scatter2(const int* __restrict__ row,
                                                  const int* __restrict__ col,
                                                  const float* __restrict__ w,
                                                  const float* __restrict__ dinv,
                                                  const float* __restrict__ h2,
                                                  float* __restrict__ out, int E) {
    int i = blockIdx.x * blockDim.x + threadIdx.x;
    if (i >= E) return;
    int r = row[i], c = col[i];
    float nw = dinv[r] * w[i] * dinv[c];
    atomicAdd(&out[(size_t)c * 2 + 0], nw * h2[(size_t)r * 2 + 0]);
    atomicAdd(&out[(size_t)c * 2 + 1], nw * h2[(size_t)r * 2 + 1]);
}

__global__ __launch_bounds__(256) void k_final(const float* __restrict__ h2,
                                               const float* __restrict__ dinv,
                                               const float* __restrict__ b2,
                                               float* __restrict__ out, int n) {
    int i = blockIdx.x * blockDim.x + threadIdx.x;
    if (i >= n) return;
    float dv = dinv[i];
    float cs = dv * dv;
    float v0 = out[(size_t)i * 2 + 0] + cs * h2[(size_t)i * 2 + 0] + b2[0];
    float v1 = out[(size_t)i * 2 + 1] + cs * h2[(size_t)i * 2 + 1] + b2[1];
    float m = fmaxf(v0, v1);
    float lse = m + logf(expf(v0 - m) + expf(v1 - m));
    out[(size_t)i * 2 + 0] = v0 - lse;
    out[(size_t)i * 2 + 1] = v1 - lse;
}

// ---------------- launch ----------------

static inline size_t align64(size_t x) { return (x + 63) & ~(size_t)63; }

extern "C" void kernel_launch(void* const* d_in, const int* in_sizes, int n_in,
                              void* d_out, int out_size, void* d_ws, size_t ws_size,
                              hipStream_t stream) {
    const float* x  = (const float*)d_in[0];
    const int*   ei = (const int*)d_in[1];
    const float* ew = (const float*)d_in[2];
    const float* W1 = (const float*)d_in[3];
    const float* b1 = (const float*)d_in[4];
    const float* W2 = (const float*)d_in[5];
    const float* b2 = (const float*)d_in[6];

    const int n = in_sizes[0] / 11;
    const int E = in_sizes[2];
    const int* rowp = ei;       // sources
    const int* colp = ei + E;   // targets

    const int TB = 256;
    const int gN = (n + TB - 1) / TB;
    const int gE = (E + TB - 1) / TB;

    const int NB = (n + BKT - 1) / BKT;            // dst buckets
    const int CH = (E + NBLK - 1) / NBLK;          // edges per partition block

    float* outf = (float*)d_out;

    // --- workspace layout ---
    char* base = (char*)d_ws;
    size_t M = (size_t)NBLK * NB;
    size_t o_hist = 0;                                        // u32 M
    size_t o_base = align64(o_hist + M * 4);                  // u32 M
    size_t o_kb   = align64(o_base + M * 4);                  // u32 NB+2
    size_t o_dinv = align64(o_kb + (size_t)(NB + 2) * 4);     // f32 n
    size_t o_xs0  = align64(o_dinv + (size_t)n * 4);          // f16 4n (8B rows)
    size_t o_xs1  = align64(o_xs0 + (size_t)n * 8);
    size_t o_xs2  = align64(o_xs1 + (size_t)n * 8);
    size_t o_ag0  = align64(o_xs2 + (size_t)n * 8);           // f32x4 n
    size_t o_ag1  = align64(o_ag0 + (size_t)n * 16);
    size_t o_ag2  = align64(o_ag1 + (size_t)n * 16);
    size_t o_h2   = align64(o_ag2 + (size_t)n * 16);          // f32 2n
    size_t o_run  = align64(o_h2 + (size_t)n * 2 * 4);        // u32 n+BKT+2
    size_t o_edge = align64(o_run + (size_t)(n + BKT + 2) * 4); // u64 E
    size_t o_edge2 = align64(o_edge + (size_t)E * 8);         // u64 E
    size_t needed = align64(o_edge2 + (size_t)E * 8);

    if (ws_size >= needed && n <= (1 << 19) && NB <= NBMAX) {
        u32*    hist_g = (u32*)(base + o_hist);
        u32*    base_g = (u32*)(base + o_base);
        u32*    kb     = (u32*)(base + o_kb);
        float*  dinv_g = (float*)(base + o_dinv);
        f16*    xs0    = (f16*)(base + o_xs0);
        f16*    xs1    = (f16*)(base + o_xs1);
        f16*    xs2    = (f16*)(base + o_xs2);
        float4* agg0   = (float4*)(base + o_ag0);
        float4* agg1   = (float4*)(base + o_ag1);
        float4* agg2   = (float4*)(base + o_ag2);
        float*  h2s    = (float*)(base + o_h2);
        u32*    runst  = (u32*)(base + o_run);
        u64*    edge_g = (u64*)(base + o_edge);
        u64*    edge2_g = (u64*)(base + o_edge2);

        const int KBg = (NB + 255) / 256;

        k_count<<<NBLK, TB, 0, stream>>>(colp, hist_g, NB, E, CH);
        k_colsum<<<KBg, TB, 0, stream>>>(hist_g, kb, NB);
        k_scan_sums32<<<1, TB, 0, stream>>>(kb, NB);           // kb -> exclusive bases
        k_basefill<<<KBg, TB, 0, stream>>>(hist_g, kb, base_g, NB);
        k_scatter<<<NBLK, 512, 0, stream>>>(rowp, colp, ew, base_g, edge_g, NB, E, CH);
        k_csrsort<<<NB, 512, 0, stream>>>(edge_g, kb, edge2_g, runst, dinv_g, NB, n, E);
        k_prep<<<gN, TB, 0, stream>>>(x, dinv_g, xs0, xs1, xs2, n);
        k_pass<<<gN, TB, 0, stream>>>(edge2_g, runst, xs0, agg0, n);
        k_pass<<<gN, TB, 0, stream>>>(edge2_g, runst, xs1, agg1, n);
        k_pass<<<gN, TB, 0, stream>>>(edge2_g, runst, xs2, agg2, n);
        k_mlp<<<gN, TB, 0, stream>>>(agg0, agg1, agg2, dinv_g, W1, b1, W2, h2s, n);
        k_pull2_csr<<<gN, TB, 0, stream>>>(edge2_g, runst, h2s, dinv_g, b2, outf, n);
    } else {
        // fallback: atomic-scatter path (R1)
        float* ws   = (float*)d_ws;
        float* dinv = ws;
        float* h1   = ws + (size_t)n;
        float* acc1 = ws + (size_t)n * 17;

        k_init_deg<<<gN, TB, 0, stream>>>(dinv, n);
        k_deg_accum<<<gE, TB, 0, stream>>>(colp, ew, dinv, E);
        k_rsqrt<<<gN, TB, 0, stream>>>(dinv, n);

        k_gemm1_plain<<<gN, TB, 0, stream>>>(x, W1, h1, n);
        hipMemsetAsync(acc1, 0, (size_t)n * 16 * sizeof(float), stream);
        k_scatter16<<<gE, TB, 0, stream>>>(rowp, colp, ew, dinv, h1, acc1, E);
        k_post1<<<gN, TB, 0, stream>>>(h1, dinv, b1, acc1, n);

        float* h2 = h1;
        k_gemm2<<<gN, TB, 0, stream>>>(acc1, W2, h2, n);
        hipMemsetAsync(outf, 0, (size_t)n * 2 * sizeof(float), stream);
        k_scatter2<<<gE, TB, 0, stream>>>(rowp, colp, ew, dinv, h2, outf, E);
        k_final<<<gN, TB, 0, stream>>>(h2, dinv, b2, outf, n);
    }
}

// Round 7
// 1366.644 us; speedup vs baseline: 1.2306x; 1.0482x over previous
//
#include <hip/hip_runtime.h>
#include <math.h>

// ---------------------------------------------------------------------------
// 2-layer GCN forward — ZERO global atomics.
// R14 (on R13's measured skeleton; sort chain untouched):
//  * R13's 3 slice passes were 202us each with FETCH 465MB: (a) nt edge reads
//    in the per-node walk get evicted between the 8 reuse iterations (~3.5x
//    re-fetch); (b) slicing tripled gather transactions (48M vs 16M).
//  * Fix: ONE fused 11-feature pull, split into 4 LAUNCH-SYNCHRONIZED passes
//    by src quarter (bits 17-18 of the packed row). Each launch gathers from
//    a 4MB 32B-row window (R8-proven L2-resident), ONE line per edge,
//    register accumulation, agg[n][12] partial carry (one owner per node,
//    no atomics). q=0 self-inits from xs; q=3 fuses the MLP -> h2s (k_mlp
//    deleted). All pass/pull2 edge reads are PLAIN loads (nt only on
//    genuinely single-touch coalesced streams in count/scatter/csrsort).
// Pipeline:
//   k_count/colsum/scan/basefill : dst-bucket bases (512 partitions)
//   k_scatter : staged counting-sort scatter -> edge_g (bucketed)
//   k_csrsort : per-bucket hist/scan -> runstart, dinv; staged dst-sort
//               -> edge2_g
//   k_prep    : node-parallel: xs = fp16x16(dinv*x) 32B rows (16MB)
//   k_pass x4 : per-node walk, quarter-filtered gathers from 4MB window;
//               q3 fuses MLP epilogue -> h2s
//   k_pull2_csr: per-node walk, h2s 4MB L2-resident -> log_softmax
// Fallback: R1 atomic-scatter path if ws too small / n too large.
// ---------------------------------------------------------------------------

typedef unsigned long long u64;
typedef unsigned int u32;
typedef unsigned short u16;
typedef _Float16 f16;
typedef __attribute__((ext_vector_type(8))) _Float16 f16x8;

#define BKT    512        // nodes per dst bucket (collow = 9 bits)
#define NBMAX  1024       // max buckets (=> n <= 2^19, matches row:19 packing)
#define NBLK   512        // partition blocks for count/scatter
#define CHUNK  4096       // staged chunk (8 edges x 512 threads)

// ---------------- count / scan / basefill ----------------

__global__ __launch_bounds__(256) void k_count(const int* __restrict__ col,
                                               u32* __restrict__ hist_g,
                                               int NB, int E, int CH) {
    __shared__ u32 cnt[NBMAX];
    for (int b = threadIdx.x; b < NB; b += 256) cnt[b] = 0;
    __syncthreads();
    int blk = blockIdx.x;
    int s = blk * CH, e = min(s + CH, E);
    for (int i = s + threadIdx.x; i < e; i += 256) {
        int c = __builtin_nontemporal_load(col + i);
        atomicAdd(&cnt[c >> 9], 1u);               // LDS atomic
    }
    __syncthreads();
    for (int b = threadIdx.x; b < NB; b += 256)
        hist_g[(size_t)blk * NB + b] = cnt[b];     // coalesced
}

__global__ __launch_bounds__(256) void k_colsum(const u32* __restrict__ hist_g,
                                                u32* __restrict__ colsum, int NB) {
    int k = blockIdx.x * 256 + threadIdx.x;
    if (k >= NB) return;
    u32 s = 0;
    for (int j = 0; j < NBLK; j++) s += hist_g[(size_t)j * NB + k];
    colsum[k] = s;
}

__global__ __launch_bounds__(256) void k_scan_sums32(u32* __restrict__ bsum, int nb) {
    __shared__ u32 s[256];
    __shared__ u32 carry;
    int t = threadIdx.x;
    if (t == 0) carry = 0;
    __syncthreads();
    int chunks = (nb + 255) / 256;
    for (int ch = 0; ch < chunks; ch++) {
        int i = ch * 256 + t;
        u32 v = (i < nb) ? bsum[i] : 0;
        s[t] = v;
        __syncthreads();
        for (int off = 1; off < 256; off <<= 1) {
            u32 u = (t >= off) ? s[t - off] : 0;
            __syncthreads();
            s[t] += u;
            __syncthreads();
        }
        u32 incl = s[t];
        u32 my_carry = carry;
        if (i < nb) bsum[i] = incl - v + my_carry;   // exclusive
        __syncthreads();
        if (t == 0) carry = my_carry + s[255];
        __syncthreads();
    }
}

__global__ __launch_bounds__(256) void k_basefill(const u32* __restrict__ hist_g,
                                                  const u32* __restrict__ keybase,
                                                  u32* __restrict__ base_g, int NB) {
    int k = blockIdx.x * 256 + threadIdx.x;
    if (k >= NB) return;
    u32 run = keybase[k];
    for (int j = 0; j < NBLK; j++) {
        base_g[(size_t)j * NB + k] = run;
        run += hist_g[(size_t)j * NB + k];
    }
}

// ---------------- staged counting-sort scatter (R13-measured) ----------------

__global__ __launch_bounds__(512) void k_scatter(const int* __restrict__ row,
                                                 const int* __restrict__ col,
                                                 const float* __restrict__ w,
                                                 const u32* __restrict__ base_g,
                                                 u64* __restrict__ edge_g,
                                                 int NB, int E, int CH) {
    __shared__ u64 stage[CHUNK];      // 32KB
    __shared__ u16 skey[CHUNK];       // 8KB
    __shared__ u32 cursor[NBMAX];     // 4KB
    __shared__ u32 ccnt[NBMAX];       // 4KB
    __shared__ u32 cbase[NBMAX];      // 4KB
    __shared__ u32 sscan[512];        // 2KB
    int t = threadIdx.x;
    int blk = blockIdx.x;
    for (int b = t; b < NB; b += 512) cursor[b] = base_g[(size_t)blk * NB + b];
    int s = blk * CH, e = min(s + CH, E);
    for (int c0 = s; c0 < e; c0 += CHUNK) {
        int cend = min(c0 + CHUNK, e);
        for (int b = t; b < NB; b += 512) ccnt[b] = 0;
        __syncthreads();
        u64 rec[8]; u32 rnk[8]; int key[8];
#pragma unroll
        for (int q = 0; q < 8; q++) {
            int i = c0 + q * 512 + t;
            if (i < cend) {
                int c  = __builtin_nontemporal_load(col + i);
                int r  = __builtin_nontemporal_load(row + i);
                float wv = __builtin_nontemporal_load(w + i);
                int k = c >> 9;
                rec[q] = ((u64)__float_as_uint(wv) << 32)
                       | ((u64)(u32)(c & 511) << 19) | (u64)(u32)r;
                key[q] = k;
                rnk[q] = atomicAdd(&ccnt[k], 1u);
            } else key[q] = -1;
        }
        __syncthreads();
        u32 a0 = (2 * t     < NB) ? ccnt[2 * t]     : 0;
        u32 a1 = (2 * t + 1 < NB) ? ccnt[2 * t + 1] : 0;
        sscan[t] = a0 + a1;
        __syncthreads();
        for (int d = 1; d < 512; d <<= 1) {
            u32 v = (t >= d) ? sscan[t - d] : 0;
            __syncthreads();
            sscan[t] += v;
            __syncthreads();
        }
        u32 bse = (t > 0) ? sscan[t - 1] : 0;
        if (2 * t     < NB) cbase[2 * t]     = bse;
        if (2 * t + 1 < NB) cbase[2 * t + 1] = bse + a0;
        __syncthreads();
#pragma unroll
        for (int q = 0; q < 8; q++) {
            if (key[q] >= 0) {
                u32 slot = cbase[key[q]] + rnk[q];
                stage[slot] = rec[q];
                skey[slot] = (u16)key[q];
            }
        }
        __syncthreads();
        int tot = cend - c0;
        for (int j = t; j < tot; j += 512) {
            int k = skey[j];
            edge_g[cursor[k] + (u32)j - cbase[k]] = stage[j];
        }
        __syncthreads();
        for (int b = t; b < NB; b += 512) cursor[b] += ccnt[b];
        __syncthreads();
    }
}

// ---------------- csrsort: hist+degw -> runstart,dinv ; staged dst-sort ----------------

__global__ __launch_bounds__(512) void k_csrsort(const u64* __restrict__ edge_g,
                                                 const u32* __restrict__ kb,
                                                 u64* __restrict__ edge2_g,
                                                 u32* __restrict__ runstart,
                                                 float* __restrict__ dinv_g,
                                                 int NB, int n, int E) {
    __shared__ u64 stage[CHUNK];      // 32KB
    __shared__ u16 skey[CHUNK];       // 8KB
    __shared__ u32 cnt[BKT];          // 2KB
    __shared__ float sdeg[BKT];       // 2KB
    __shared__ u32 cur[BKT];          // 2KB
    __shared__ u32 ccnt[BKT];         // 2KB
    __shared__ u32 cbase[BKT];        // 2KB
    int t = threadIdx.x;              // 512 threads; t owns dst t
    int b = blockIdx.x;
    int node0 = b << 9;
    int s = (int)kb[b];
    int e = (b + 1 < NB) ? (int)kb[b + 1] : E;
    cnt[t] = 0;
    sdeg[t] = 1.0f;                   // self-loop weight
    __syncthreads();
    for (int i = s + t; i < e; i += 512) {
        u64 rec = __builtin_nontemporal_load(edge_g + i);
        int cl = (int)(((u32)rec >> 19) & 511u);
        atomicAdd(&cnt[cl], 1u);
        atomicAdd(&sdeg[cl], __uint_as_float((u32)(rec >> 32)));
    }
    __syncthreads();
    ccnt[t] = cnt[t];
    __syncthreads();
    for (int d = 1; d < 512; d <<= 1) {
        u32 v = (t >= d) ? ccnt[t - d] : 0;
        __syncthreads();
        ccnt[t] += v;
        __syncthreads();
    }
    u32 mystart = (u32)s + ccnt[t] - cnt[t];
    cur[t] = mystart;
    runstart[node0 + t] = mystart;
    if (t == 511) runstart[node0 + 512] = (u32)e;
    if (node0 + t < n) dinv_g[node0 + t] = rsqrtf(sdeg[t]);
    __syncthreads();
    for (int c0 = s; c0 < e; c0 += CHUNK) {
        int cend = min(c0 + CHUNK, e);
        ccnt[t] = 0;
        __syncthreads();
        u64 rec[8]; u32 rnk[8]; int key[8];
#pragma unroll
        for (int q = 0; q < 8; q++) {
            int i = c0 + q * 512 + t;
            if (i < cend) {
                u64 r = __builtin_nontemporal_load(edge_g + i);
                int cl = (int)(((u32)r >> 19) & 511u);
                rec[q] = r;
                key[q] = cl;
                rnk[q] = atomicAdd(&ccnt[cl], 1u);
            } else key[q] = -1;
        }
        __syncthreads();
        cbase[t] = ccnt[t];
        __syncthreads();
        for (int d = 1; d < 512; d <<= 1) {
            u32 v = (t >= d) ? cbase[t - d] : 0;
            __syncthreads();
            cbase[t] += v;
            __syncthreads();
        }
        u32 myexc = cbase[t] - ccnt[t];
        __syncthreads();
        cbase[t] = myexc;
        __syncthreads();
#pragma unroll
        for (int q = 0; q < 8; q++) {
            if (key[q] >= 0) {
                u32 slot = cbase[key[q]] + rnk[q];
                stage[slot] = rec[q];
                skey[slot] = (u16)key[q];
            }
        }
        __syncthreads();
        int tot = cend - c0;
        for (int j = t; j < tot; j += 512) {
            int k = skey[j];
            edge2_g[cur[k] + (u32)j - cbase[k]] = stage[j];
        }
        __syncthreads();
        cur[t] += ccnt[t];
        __syncthreads();
    }
}

// ---------------- prep (node-parallel): xs = fp16x16(dinv * x), 32B rows ----------------

__global__ __launch_bounds__(256) void k_prep(const float* __restrict__ x,
                                              const float* __restrict__ dinv_g,
                                              f16* __restrict__ xs, int n) {
    int node = blockIdx.x * 256 + threadIdx.x;
    if (node >= n) return;
    float dv = dinv_g[node];
    const float* xp = x + (size_t)node * 11;
    f16x8 lo, hi;
#pragma unroll
    for (int k = 0; k < 8; k++) lo[k] = (f16)(dv * xp[k]);
    hi[0] = (f16)(dv * xp[8]);
    hi[1] = (f16)(dv * xp[9]);
    hi[2] = (f16)(dv * xp[10]);
    hi[3] = (f16)0.f; hi[4] = (f16)0.f; hi[5] = (f16)0.f;
    hi[6] = (f16)0.f; hi[7] = (f16)0.f;
    f16x8* dst = (f16x8*)(xs + ((size_t)node << 4));
    dst[0] = lo;
    dst[1] = hi;
}

// ---------------- quartered fused pull pass ----------------
// Launch q processes edges with src in [q<<17, (q+1)<<17): gathers hit a 4MB
// L2-resident window of 32B rows. One owner thread per node -> register
// accumulation, zero atomics. first: init from xs self; fin: fused MLP->h2s.

__global__ __launch_bounds__(256) void k_pass(const u64* __restrict__ edge2_g,
                                              const u32* __restrict__ runstart,
                                              const f16* __restrict__ xs,
                                              float4* __restrict__ agg0,
                                              float4* __restrict__ agg1,
                                              float4* __restrict__ agg2,
                                              const float* __restrict__ dinv_g,
                                              const float* __restrict__ W1,
                                              const float* __restrict__ b1,
                                              const float* __restrict__ W2,
                                              float* __restrict__ h2s,
                                              int n, int q, int first, int fin) {
    __shared__ float sW1[176];
    __shared__ float sb1[16];
    __shared__ float sW2[32];
    if (fin) {
        for (int t = threadIdx.x; t < 176; t += 256) sW1[t] = W1[t];
        if (threadIdx.x < 16) sb1[threadIdx.x] = b1[threadIdx.x];
        if (threadIdx.x >= 32 && threadIdx.x < 64) sW2[threadIdx.x - 32] = W2[threadIdx.x - 32];
        __syncthreads();
    }
    int node = blockIdx.x * 256 + threadIdx.x;
    if (node >= n) return;
    float a[11];
    if (first) {
        const f16x8* self = (const f16x8*)(xs + ((size_t)node << 4));
        f16x8 slo = self[0], shi = self[1];
#pragma unroll
        for (int k = 0; k < 8; k++) a[k] = (float)slo[k];
        a[8] = (float)shi[0]; a[9] = (float)shi[1]; a[10] = (float)shi[2];
    } else {
        float4 v0 = agg0[node], v1 = agg1[node], v2 = agg2[node];
        a[0] = v0.x; a[1] = v0.y; a[2]  = v0.z; a[3] = v0.w;
        a[4] = v1.x; a[5] = v1.y; a[6]  = v1.z; a[7] = v1.w;
        a[8] = v2.x; a[9] = v2.y; a[10] = v2.z;
    }
    u32 qtag = (u32)q << 17;
    int p = (int)runstart[node], pe = (int)runstart[node + 1];
#define PROCQ(rec) { u32 lo_ = (u32)(rec); \
    if ((lo_ & 0x60000u) == qtag) { \
        const f16x8* qp_ = (const f16x8*)(xs + ((size_t)(lo_ & 0x7FFFFu) << 4)); \
        f16x8 l_ = qp_[0], h_ = qp_[1]; \
        float wv_ = __uint_as_float((u32)((rec) >> 32)); \
        a[0] += wv_ * (float)l_[0]; a[1] += wv_ * (float)l_[1]; \
        a[2] += wv_ * (float)l_[2]; a[3] += wv_ * (float)l_[3]; \
        a[4] += wv_ * (float)l_[4]; a[5] += wv_ * (float)l_[5]; \
        a[6] += wv_ * (float)l_[6]; a[7] += wv_ * (float)l_[7]; \
        a[8] += wv_ * (float)h_[0]; a[9] += wv_ * (float)h_[1]; \
        a[10] += wv_ * (float)h_[2]; } }
    for (; p + 3 < pe; p += 4) {          // plain loads: lines reused across iters
        u64 r0 = edge2_g[p],     r1 = edge2_g[p + 1];
        u64 r2 = edge2_g[p + 2], r3 = edge2_g[p + 3];
        PROCQ(r0) PROCQ(r1) PROCQ(r2) PROCQ(r3)
    }
    for (; p < pe; p++) {
        u64 r0 = edge2_g[p];
        PROCQ(r0)
    }
#undef PROCQ
    if (!fin) {
        float4 o0, o1, o2;
        o0.x = a[0]; o0.y = a[1]; o0.z = a[2];  o0.w = a[3];
        o1.x = a[4]; o1.y = a[5]; o1.z = a[6];  o1.w = a[7];
        o2.x = a[8]; o2.y = a[9]; o2.z = a[10]; o2.w = 0.f;
        agg0[node] = o0; agg1[node] = o1; agg2[node] = o2;
    } else {
        float dv = dinv_g[node];
#pragma unroll
        for (int k = 0; k < 11; k++) a[k] *= dv;
        float o0 = 0.f, o1 = 0.f;
#pragma unroll
        for (int f = 0; f < 16; f++) {
            float hh = sb1[f];
#pragma unroll
            for (int k = 0; k < 11; k++) hh += a[k] * sW1[k * 16 + f];
            hh = fmaxf(hh, 0.f);
            o0 += hh * sW2[f * 2 + 0];
            o1 += hh * sW2[f * 2 + 1];
        }
        float2 ov; ov.x = dv * o0; ov.y = dv * o1;   // h2s = dinv * h2
        *(float2*)(h2s + ((size_t)node << 1)) = ov;
    }
}

// ---------------- CSR pull layer 2 (no LDS, no atomics, plain loads) ----------------

__global__ __launch_bounds__(256) void k_pull2_csr(const u64* __restrict__ edge2_g,
                                                   const u32* __restrict__ runstart,
                                                   const float* __restrict__ h2s,
                                                   const float* __restrict__ dinv_g,
                                                   const float* __restrict__ b2,
                                                   float* __restrict__ out, int n) {
    int node = blockIdx.x * 256 + threadIdx.x;
    if (node >= n) return;
    float2 selfv = *(const float2*)(h2s + (size_t)node * 2);
    float a0 = selfv.x, a1 = selfv.y;
    int p = (int)runstart[node], pe = (int)runstart[node + 1];
    for (; p + 3 < pe; p += 4) {
        u64 r0 = edge2_g[p],     r1 = edge2_g[p + 1];
        u64 r2 = edge2_g[p + 2], r3 = edge2_g[p + 3];
        float2 g0 = *(const float2*)(h2s + (size_t)((u32)r0 & 0x7FFFFu) * 2);
        float2 g1 = *(const float2*)(h2s + (size_t)((u32)r1 & 0x7FFFFu) * 2);
        float2 g2 = *(const float2*)(h2s + (size_t)((u32)r2 & 0x7FFFFu) * 2);
        float2 g3 = *(const float2*)(h2s + (size_t)((u32)r3 & 0x7FFFFu) * 2);
        float w0 = __uint_as_float((u32)(r0 >> 32));
        float w1 = __uint_as_float((u32)(r1 >> 32));
        float w2 = __uint_as_float((u32)(r2 >> 32));
        float w3 = __uint_as_float((u32)(r3 >> 32));
        a0 += w0 * g0.x + w1 * g1.x + w2 * g2.x + w3 * g3.x;
        a1 += w0 * g0.y + w1 * g1.y + w2 * g2.y + w3 * g3.y;
    }
    for (; p < pe; p++) {
        u64 r0 = edge2_g[p];
        float2 g0 = *(const float2*)(h2s + (size_t)((u32)r0 & 0x7FFFFu) * 2);
        float w0 = __uint_as_float((u32)(r0 >> 32));
        a0 += w0 * g0.x;
        a1 += w0 * g0.y;
    }
    float dv = dinv_g[node];
    float v0 = dv * a0 + b2[0];
    float v1 = dv * a1 + b2[1];
    float m = fmaxf(v0, v1);
    float lse = m + logf(expf(v0 - m) + expf(v1 - m));
    float2 ov; ov.x = v0 - lse; ov.y = v1 - lse;
    *(float2*)(out + (size_t)node * 2) = ov;
}

// ---------------- fallback atomic-scatter kernels (R1 proven path) ----------------

__global__ __launch_bounds__(256) void k_init_deg(float* deg, int n) {
    int i = blockIdx.x * blockDim.x + threadIdx.x;
    if (i < n) deg[i] = 1.0f;
}

__global__ __launch_bounds__(256) void k_deg_accum(const int* __restrict__ col,
                                                   const float* __restrict__ w,
                                                   float* __restrict__ deg, int E) {
    int i = blockIdx.x * blockDim.x + threadIdx.x;
    if (i < E) atomicAdd(&deg[col[i]], w[i]);
}

__global__ __launch_bounds__(256) void k_rsqrt(float* deg, int n) {
    int i = blockIdx.x * blockDim.x + threadIdx.x;
    if (i < n) {
        float d = deg[i];
        deg[i] = (d > 0.0f) ? rsqrtf(d) : 0.0f;
    }
}

__global__ __launch_bounds__(256) void k_gemm1_plain(const float* __restrict__ x,
                                                     const float* __restrict__ W1,
                                                     float* __restrict__ h1, int n) {
    __shared__ float sW[176];
    for (int t = threadIdx.x; t < 176; t += blockDim.x) sW[t] = W1[t];
    __syncthreads();
    int i = blockIdx.x * blockDim.x + threadIdx.x;
    if (i >= n) return;
    float xi[11];
#pragma unroll
    for (int k = 0; k < 11; k++) xi[k] = x[(size_t)i * 11 + k];
#pragma unroll
    for (int f = 0; f < 16; f++) {
        float acc = 0.0f;
#pragma unroll
        for (int k = 0; k < 11; k++) acc += xi[k] * sW[k * 16 + f];
        h1[(size_t)i * 16 + f] = acc;
    }
}

__global__ __launch_bounds__(256) void k_scatter16(const int* __restrict__ row,
                                                   const int* __restrict__ col,
                                                   const float* __restrict__ w,
                                                   const float* __restrict__ dinv,
                                                   const float* __restrict__ h1,
                                                   float* __restrict__ acc, int E) {
    int i = blockIdx.x * blockDim.x + threadIdx.x;
    if (i >= E) return;
    int r = row[i], c = col[i];
    float nw = dinv[r] * w[i] * dinv[c];
    const float4* hr = (const float4*)(h1 + (size_t)r * 16);
    float* o = acc + (size_t)c * 16;
#pragma unroll
    for (int q = 0; q < 4; q++) {
        float4 hv = hr[q];
        atomicAdd(o + q * 4 + 0, nw * hv.x);
        atomicAdd(o + q * 4 + 1, nw * hv.y);
        atomicAdd(o + q * 4 + 2, nw * hv.z);
        atomicAdd(o + q * 4 + 3, nw * hv.w);
    }
}

__global__ __launch_bounds__(256) void k_post1(const float* __restrict__ h1,
                                               const float* __restrict__ dinv,
                                               const float* __restrict__ b1,
                                               float* __restrict__ acc, int n) {
    int i = blockIdx.x * blockDim.x + threadIdx.x;
    if (i >= n) return;
    float dv = dinv[i];
    float cs = dv * dv;
#pragma unroll
    for (int f = 0; f < 16; f++) {
        float v = acc[(size_t)i * 16 + f] + cs * h1[(size_t)i * 16 + f] + b1[f];
        acc[(size_t)i * 16 + f] = v > 0.0f ? v : 0.0f;
    }
}

__global__ __launch_bounds__(256) void k_gemm2(const float* __restrict__ hrelu,
                                               const float* __restrict__ W2,
                                               float* __restrict__ h2, int n) {
    __shared__ float sW[32];
    for (int t = threadIdx.x; t < 32; t += blockDim.x) sW[t] = W2[t];
    __syncthreads();
    int i = blockIdx.x * blockDim.x + threadIdx.x;
    if (i >= n) return;
    float a0 = 0.0f, a1 = 0.0f;
#pragma unroll
    for (int f = 0; f < 16; f++) {
        float h = hrelu[(size_t)i * 16 + f];
        a0 += h * sW[f * 2 + 0];
        a1 += h * sW[f * 2 + 1];
    }
    h2[(size_t)i * 2 + 0] = a0;
    h2[(size_t)i * 2 + 1] = a1;
}

__global__ __launch_bounds__(256) void k_scatter2(const int* __restrict__ row,
                                                  const int* __restrict__ col,
                                                  const float* __restrict__ w,
                                                  const float* __restrict__ dinv,
                                                  const float* __restrict__ h2,
                                                  float* __restrict__ out, int E) {
    int i = blockIdx.x * blockDim.x + threadIdx.x;
    if (i >= E) return;
    int r = row[i], c = col[i];
    float nw = dinv[r] * w[i] * dinv[c];
    atomicAdd(&out[(size_t)c * 2 + 0], nw * h2[(size_t)r * 2 + 0]);
    atomicAdd(&out[(size_t)c * 2 + 1], nw * h2[(size_t)r * 2 + 1]);
}

__global__ __launch_bounds__(256) void k_final(const float* __restrict__ h2,
                                               const float* __restrict__ dinv,
                                               const float* __restrict__ b2,
                                               float* __restrict__ out, int n) {
    int i = blockIdx.x * blockDim.x + threadIdx.x;
    if (i >= n) return;
    float dv = dinv[i];
    float cs = dv * dv;
    float v0 = out[(size_t)i * 2 + 0] + cs * h2[(size_t)i * 2 + 0] + b2[0];
    float v1 = out[(size_t)i * 2 + 1] + cs * h2[(size_t)i * 2 + 1] + b2[1];
    float m = fmaxf(v0, v1);
    float lse = m + logf(expf(v0 - m) + expf(v1 - m));
    out[(size_t)i * 2 + 0] = v0 - lse;
    out[(size_t)i * 2 + 1] = v1 - lse;
}

// ---------------- launch ----------------

static inline size_t align64(size_t x) { return (x + 63) & ~(size_t)63; }

extern "C" void kernel_launch(void* const* d_in, const int* in_sizes, int n_in,
                              void* d_out, int out_size, void* d_ws, size_t ws_size,
                              hipStream_t stream) {
    const float* x  = (const float*)d_in[0];
    const int*   ei = (const int*)d_in[1];
    const float* ew = (const float*)d_in[2];
    const float* W1 = (const float*)d_in[3];
    const float* b1 = (const float*)d_in[4];
    const float* W2 = (const float*)d_in[5];
    const float* b2 = (const float*)d_in[6];

    const int n = in_sizes[0] / 11;
    const int E = in_sizes[2];
    const int* rowp = ei;       // sources
    const int* colp = ei + E;   // targets

    const int TB = 256;
    const int gN = (n + TB - 1) / TB;
    const int gE = (E + TB - 1) / TB;

    const int NB = (n + BKT - 1) / BKT;            // dst buckets
    const int CH = (E + NBLK - 1) / NBLK;          // edges per partition block

    float* outf = (float*)d_out;

    // --- workspace layout ---
    char* base = (char*)d_ws;
    size_t M = (size_t)NBLK * NB;
    size_t o_hist = 0;                                        // u32 M
    size_t o_base = align64(o_hist + M * 4);                  // u32 M
    size_t o_kb   = align64(o_base + M * 4);                  // u32 NB+2
    size_t o_dinv = align64(o_kb + (size_t)(NB + 2) * 4);     // f32 n
    size_t o_xs   = align64(o_dinv + (size_t)n * 4);          // f16 16n (32B rows)
    size_t o_ag0  = align64(o_xs + (size_t)n * 32);           // f32x4 n
    size_t o_ag1  = align64(o_ag0 + (size_t)n * 16);
    size_t o_ag2  = align64(o_ag1 + (size_t)n * 16);
    size_t o_h2   = align64(o_ag2 + (size_t)n * 16);          // f32 2n
    size_t o_run  = align64(o_h2 + (size_t)n * 2 * 4);        // u32 n+BKT+2
    size_t o_edge = align64(o_run + (size_t)(n + BKT + 2) * 4); // u64 E
    size_t o_edge2 = align64(o_edge + (size_t)E * 8);         // u64 E
    size_t needed = align64(o_edge2 + (size_t)E * 8);

    if (ws_size >= needed && n <= (1 << 19) && NB <= NBMAX) {
        u32*    hist_g = (u32*)(base + o_hist);
        u32*    base_g = (u32*)(base + o_base);
        u32*    kb     = (u32*)(base + o_kb);
        float*  dinv_g = (float*)(base + o_dinv);
        f16*    xs     = (f16*)(base + o_xs);
        float4* agg0   = (float4*)(base + o_ag0);
        float4* agg1   = (float4*)(base + o_ag1);
        float4* agg2   = (float4*)(base + o_ag2);
        float*  h2s    = (float*)(base + o_h2);
        u32*    runst  = (u32*)(base + o_run);
        u64*    edge_g = (u64*)(base + o_edge);
        u64*    edge2_g = (u64*)(base + o_edge2);

        const int KBg = (NB + 255) / 256;

        k_count<<<NBLK, TB, 0, stream>>>(colp, hist_g, NB, E, CH);
        k_colsum<<<KBg, TB, 0, stream>>>(hist_g, kb, NB);
        k_scan_sums32<<<1, TB, 0, stream>>>(kb, NB);           // kb -> exclusive bases
        k_basefill<<<KBg, TB, 0, stream>>>(hist_g, kb, base_g, NB);
        k_scatter<<<NBLK, 512, 0, stream>>>(rowp, colp, ew, base_g, edge_g, NB, E, CH);
        k_csrsort<<<NB, 512, 0, stream>>>(edge_g, kb, edge2_g, runst, dinv_g, NB, n, E);
        k_prep<<<gN, TB, 0, stream>>>(x, dinv_g, xs, n);
        // 4 launch-synchronized quarter passes (src-windowed gathers)
        k_pass<<<gN, TB, 0, stream>>>(edge2_g, runst, xs, agg0, agg1, agg2,
                                      dinv_g, W1, b1, W2, h2s, n, 0, 1, 0);
        k_pass<<<gN, TB, 0, stream>>>(edge2_g, runst, xs, agg0, agg1, agg2,
                                      dinv_g, W1, b1, W2, h2s, n, 1, 0, 0);
        k_pass<<<gN, TB, 0, stream>>>(edge2_g, runst, xs, agg0, agg1, agg2,
                                      dinv_g, W1, b1, W2, h2s, n, 2, 0, 0);
        k_pass<<<gN, TB, 0, stream>>>(edge2_g, runst, xs, agg0, agg1, agg2,
                                      dinv_g, W1, b1, W2, h2s, n, 3, 0, 1);
        k_pull2_csr<<<gN, TB, 0, stream>>>(edge2_g, runst, h2s, dinv_g, b2, outf, n);
    } else {
        // fallback: atomic-scatter path (R1)
        float* ws   = (float*)d_ws;
        float* dinv = ws;
        float* h1   = ws + (size_t)n;
        float* acc1 = ws + (size_t)n * 17;

        k_init_deg<<<gN, TB, 0, stream>>>(dinv, n);
        k_deg_accum<<<gE, TB, 0, stream>>>(colp, ew, dinv, E);
        k_rsqrt<<<gN, TB, 0, stream>>>(dinv, n);

        k_gemm1_plain<<<gN, TB, 0, stream>>>(x, W1, h1, n);
        hipMemsetAsync(acc1, 0, (size_t)n * 16 * sizeof(float), stream);
        k_scatter16<<<gE, TB, 0, stream>>>(rowp, colp, ew, dinv, h1, acc1, E);
        k_post1<<<gN, TB, 0, stream>>>(h1, dinv, b1, acc1, n);

        float* h2 = h1;
        k_gemm2<<<gN, TB, 0, stream>>>(acc1, W2, h2, n);
        hipMemsetAsync(outf, 0, (size_t)n * 2 * sizeof(float), stream);
        k_scatter2<<<gE, TB, 0, stream>>>(rowp, colp, ew, dinv, h2, outf, E);
        k_final<<<gN, TB, 0, stream>>>(h2, dinv, b2, outf, n);
    }
}